// Round 1
// baseline (169.498 us; speedup 1.0000x reference)
//
#include <hip/hip_runtime.h>
#include <hip/hip_bf16.h>
#include <stdint.h>

typedef __attribute__((ext_vector_type(8))) __bf16 bf16x8;
typedef __attribute__((ext_vector_type(4))) float f32x4;

static __device__ __forceinline__ unsigned short f2bf(float f) {
    // round-to-nearest-even fp32 -> bf16
    unsigned int u = __float_as_uint(f);
    unsigned int r = (u + 0x7fffu + ((u >> 16) & 1u)) >> 16;
    return (unsigned short)r;
}

// ---------------- Kernel 1: 2:4 prune + variance-ratio scale, fp32 -> bf16 ----------------
// One block (256 threads) per row of 1024. Each thread owns one float4 = one prune group.
__global__ __launch_bounds__(256) void prune_scale_kernel(
    const float* __restrict__ x, unsigned short* __restrict__ a)
{
    const int row = blockIdx.x;
    const int t = threadIdx.x;

    const float4 g = ((const float4*)(x + (size_t)row * 1024))[t];

    const float a0 = fabsf(g.x), a1 = fabsf(g.y), a2 = fabsf(g.z), a3 = fabsf(g.w);
    // rank = count of elements that beat me (strictly greater, or equal with lower index)
    // matches jax.lax.top_k stable tie-breaking (lower index wins)
    const int r0 = (a1 > a0) + (a2 > a0) + (a3 > a0);
    const int r1 = (a0 >= a1) + (a2 > a1) + (a3 > a1);
    const int r2 = (a0 >= a2) + (a1 >= a2) + (a3 > a2);
    const int r3 = (a0 >= a3) + (a1 >= a3) + (a2 >= a3);
    const float p0 = (r0 < 2) ? g.x : 0.0f;
    const float p1 = (r1 < 2) ? g.y : 0.0f;
    const float p2 = (r2 < 2) ? g.z : 0.0f;
    const float p3 = (r3 < 2) ? g.w : 0.0f;

    float sx  = g.x + g.y + g.z + g.w;
    float sxx = g.x*g.x + g.y*g.y + g.z*g.z + g.w*g.w;
    float sp  = p0 + p1 + p2 + p3;
    float spp = p0*p0 + p1*p1 + p2*p2 + p3*p3;

    // wave-64 butterfly-free down reduce
    #pragma unroll
    for (int off = 32; off > 0; off >>= 1) {
        sx  += __shfl_down(sx,  off);
        sxx += __shfl_down(sxx, off);
        sp  += __shfl_down(sp,  off);
        spp += __shfl_down(spp, off);
    }
    __shared__ float red[4][4];
    __shared__ float vsh;
    const int lane = t & 63, w = t >> 6;
    if (lane == 0) { red[w][0] = sx; red[w][1] = sxx; red[w][2] = sp; red[w][3] = spp; }
    __syncthreads();
    if (t == 0) {
        float SX = 0.f, SXX = 0.f, SP = 0.f, SPP = 0.f;
        #pragma unroll
        for (int i = 0; i < 4; ++i) { SX += red[i][0]; SXX += red[i][1]; SP += red[i][2]; SPP += red[i][3]; }
        const float D = 1024.0f, DM1 = 1023.0f;
        const float var_x = (SXX - SX * SX / D) / DM1;
        float var_p = (SPP - SP * SP / D) / DM1;
        var_p = fmaxf(var_p, 1e-9f);
        vsh = sqrtf(var_x / var_p);
    }
    __syncthreads();
    const float v = vsh;

    ushort4 o;
    o.x = f2bf(v * p0); o.y = f2bf(v * p1); o.z = f2bf(v * p2); o.w = f2bf(v * p3);
    ((ushort4*)(a + (size_t)row * 1024))[t] = o;
}

// ---------------- Kernel 2: weight fp32 -> bf16 ----------------
__global__ __launch_bounds__(256) void wconv_kernel(
    const float* __restrict__ w, unsigned short* __restrict__ wb)
{
    const int i = blockIdx.x * 256 + threadIdx.x;   // 4 elements each
    const float4 v = ((const float4*)w)[i];
    ushort4 o;
    o.x = f2bf(v.x); o.y = f2bf(v.y); o.z = f2bf(v.z); o.w = f2bf(v.w);
    ((ushort4*)wb)[i] = o;
}

// ---------------- Kernel 3: bf16 GEMM, C[M,N] = A[M,K] * B[N,K]^T, fp32 out ----------------
// m97 structure: 128x128 tile, BK=32, 4 waves (2x2), 4x4 16x16x32 MFMA frags per wave,
// global_load_lds width-16 staging into linear LDS, 2 barriers per K-step.
#define BM 128
#define BN 128
#define BK 32
#define KDIM 1024
#define NDIM 1024

#define GLL16(gp, lp)                                                          \
    __builtin_amdgcn_global_load_lds(                                          \
        (const __attribute__((address_space(1))) void*)(gp),                   \
        (__attribute__((address_space(3))) void*)(lp), 16, 0, 0)

__global__ __launch_bounds__(256) void gemm_bt_kernel(
    const unsigned short* __restrict__ A,   // [M][K] bf16
    const unsigned short* __restrict__ B,   // [N][K] bf16 (i.e. W row-major: [out][in])
    float* __restrict__ C)                  // [M][N] f32
{
    __shared__ alignas(16) unsigned short As[BM * BK];   // 8 KiB
    __shared__ alignas(16) unsigned short Bs[BN * BK];   // 8 KiB

    const int t  = threadIdx.x;
    const int w  = t >> 6;            // wave 0..3
    const int wr = w >> 1;            // wave row 0..1  (64-row sub-tile)
    const int wc = w & 1;             // wave col 0..1  (64-col sub-tile)
    const int fr = t & 15;            // fragment row/col within 16
    const int fq = (t >> 4) & 3;      // k-group / output row quad
    const int k8 = fq * 8;

    const int tile_n = blockIdx.x & 7;     // N/BN = 8
    const int tile_m = blockIdx.x >> 3;    // M/BM = 256

    // staging: per instr, 256 threads x 16B = 4 KiB = 64 rows of 32 bf16
    const int srow = t >> 2;          // 0..63
    const int scol = (t & 3) * 8;     // 0,8,16,24

    const unsigned short* Ag = A + (size_t)(tile_m * BM + srow) * KDIM + scol;
    const unsigned short* Bg = B + (size_t)(tile_n * BN + srow) * KDIM + scol;

    // wave-uniform LDS byte bases (HW adds lane*16)
    char* asb = (char*)As + (size_t)w * 1024;
    char* bsb = (char*)Bs + (size_t)w * 1024;

    f32x4 acc[4][4] = {};

    for (int kt = 0; kt < KDIM; kt += BK) {
        GLL16(Ag + kt,             asb);
        GLL16(Ag + 64 * KDIM + kt, asb + 4096);
        GLL16(Bg + kt,             bsb);
        GLL16(Bg + 64 * KDIM + kt, bsb + 4096);
        __syncthreads();   // drains vmcnt: tiles staged

        bf16x8 af[4], bfr[4];
        #pragma unroll
        for (int m = 0; m < 4; ++m)
            af[m] = *(const bf16x8*)(As + (wr * 64 + m * 16 + fr) * BK + k8);
        #pragma unroll
        for (int n = 0; n < 4; ++n)
            bfr[n] = *(const bf16x8*)(Bs + (wc * 64 + n * 16 + fr) * BK + k8);

        #pragma unroll
        for (int m = 0; m < 4; ++m)
            #pragma unroll
            for (int n = 0; n < 4; ++n)
                acc[m][n] = __builtin_amdgcn_mfma_f32_16x16x32_bf16(
                    af[m], bfr[n], acc[m][n], 0, 0, 0);

        __syncthreads();   // LDS reads done before next stage overwrites
    }

    // C/D layout: col = lane&15, row = (lane>>4)*4 + reg
    float* Cp = C + (size_t)(tile_m * BM + wr * 64 + fq * 4) * NDIM
                  + tile_n * BN + wc * 64 + fr;
    #pragma unroll
    for (int m = 0; m < 4; ++m)
        #pragma unroll
        for (int n = 0; n < 4; ++n)
            #pragma unroll
            for (int j = 0; j < 4; ++j)
                Cp[(size_t)(m * 16 + j) * NDIM + n * 16] = acc[m][n][j];
}

extern "C" void kernel_launch(void* const* d_in, const int* in_sizes, int n_in,
                              void* d_out, int out_size, void* d_ws, size_t ws_size,
                              hipStream_t stream) {
    const float* x  = (const float*)d_in[0];   // [4,8192,1024] fp32
    const float* wt = (const float*)d_in[1];   // [1024,1024] fp32
    float* out = (float*)d_out;                // [4,8192,1024] fp32

    unsigned short* Abf = (unsigned short*)d_ws;                    // 64 MiB
    unsigned short* Wbf = Abf + (size_t)32768 * 1024;               // +2 MiB

    prune_scale_kernel<<<32768, 256, 0, stream>>>(x, Abf);
    wconv_kernel<<<1024, 256, 0, stream>>>(wt, Wbf);
    gemm_bt_kernel<<<2048, 256, 0, stream>>>(Abf, Wbf, out);
}

// Round 2
// 123.768 us; speedup vs baseline: 1.3695x; 1.3695x over previous
//
#include <hip/hip_runtime.h>
#include <hip/hip_bf16.h>
#include <stdint.h>

typedef __attribute__((ext_vector_type(8))) __bf16 bf16x8;
typedef __attribute__((ext_vector_type(4))) float f32x4;

static __device__ __forceinline__ unsigned short f2bf(float f) {
    unsigned int u = __float_as_uint(f);
    unsigned int r = (u + 0x7fffu + ((u >> 16) & 1u)) >> 16;
    return (unsigned short)r;
}

// ---------------- Kernel 1: 2:4 prune + variance-ratio scale, fp32 -> bf16 ----------------
__global__ __launch_bounds__(256) void prune_scale_kernel(
    const float* __restrict__ x, unsigned short* __restrict__ a)
{
    const int row = blockIdx.x;
    const int t = threadIdx.x;

    const float4 g = ((const float4*)(x + (size_t)row * 1024))[t];

    const float a0 = fabsf(g.x), a1 = fabsf(g.y), a2 = fabsf(g.z), a3 = fabsf(g.w);
    const int r0 = (a1 > a0) + (a2 > a0) + (a3 > a0);
    const int r1 = (a0 >= a1) + (a2 > a1) + (a3 > a1);
    const int r2 = (a0 >= a2) + (a1 >= a2) + (a3 > a2);
    const int r3 = (a0 >= a3) + (a1 >= a3) + (a2 >= a3);
    const float p0 = (r0 < 2) ? g.x : 0.0f;
    const float p1 = (r1 < 2) ? g.y : 0.0f;
    const float p2 = (r2 < 2) ? g.z : 0.0f;
    const float p3 = (r3 < 2) ? g.w : 0.0f;

    float sx  = g.x + g.y + g.z + g.w;
    float sxx = g.x*g.x + g.y*g.y + g.z*g.z + g.w*g.w;
    float sp  = p0 + p1 + p2 + p3;
    float spp = p0*p0 + p1*p1 + p2*p2 + p3*p3;

    #pragma unroll
    for (int off = 32; off > 0; off >>= 1) {
        sx  += __shfl_down(sx,  off);
        sxx += __shfl_down(sxx, off);
        sp  += __shfl_down(sp,  off);
        spp += __shfl_down(spp, off);
    }
    __shared__ float red[4][4];
    __shared__ float vsh;
    const int lane = t & 63, w = t >> 6;
    if (lane == 0) { red[w][0] = sx; red[w][1] = sxx; red[w][2] = sp; red[w][3] = spp; }
    __syncthreads();
    if (t == 0) {
        float SX = 0.f, SXX = 0.f, SP = 0.f, SPP = 0.f;
        #pragma unroll
        for (int i = 0; i < 4; ++i) { SX += red[i][0]; SXX += red[i][1]; SP += red[i][2]; SPP += red[i][3]; }
        const float D = 1024.0f, DM1 = 1023.0f;
        const float var_x = (SXX - SX * SX / D) / DM1;
        float var_p = (SPP - SP * SP / D) / DM1;
        var_p = fmaxf(var_p, 1e-9f);
        vsh = sqrtf(var_x / var_p);
    }
    __syncthreads();
    const float v = vsh;

    ushort4 o;
    o.x = f2bf(v * p0); o.y = f2bf(v * p1); o.z = f2bf(v * p2); o.w = f2bf(v * p3);
    ((ushort4*)(a + (size_t)row * 1024))[t] = o;
}

// ---------------- Kernel 2: weight fp32 -> bf16 ----------------
__global__ __launch_bounds__(256) void wconv_kernel(
    const float* __restrict__ w, unsigned short* __restrict__ wb)
{
    const int i = blockIdx.x * 256 + threadIdx.x;
    const float4 v = ((const float4*)w)[i];
    ushort4 o;
    o.x = f2bf(v.x); o.y = f2bf(v.y); o.z = f2bf(v.z); o.w = f2bf(v.w);
    ((ushort4*)wb)[i] = o;
}

// ---------------- Kernel 3: 256x256x64 deep-pipelined bf16 GEMM (B^T), fp32 out ----------------
// 8 waves (2m x 4n), per-wave 128x64 output = acc[8][4] f32x4.
// LDS: A [2buf][2kh][256 rows][32 k] bf16 (64KB) at 0; B same at 65536. Total 128KB.
// Swizzle: 16B-granule g' = g ^ ((row>>1)&3)  (applied on global src for staging, and on reads).
// Schedule per tile t (4 phases q=(mh,ks)): stage one 16KB half per phase,
// counted vmcnt(2) once per tile at q3 BEFORE the mid-phase barrier.
#define KD 1024
#define ND 1024

#define GLL16(gp, lp)                                                          \
    __builtin_amdgcn_global_load_lds(                                          \
        (const __attribute__((address_space(1))) void*)(gp),                   \
        (__attribute__((address_space(3))) void*)(lp), 16, 0, 0)

#define ASTAGE(bufx, kh, kt) {                                                 \
    const unsigned short* _s = aG + (size_t)(kt) * 64 + (kh) * 32;             \
    char* _dp = smem + (bufx) * 32768 + (kh) * 16384 + w * 1024;               \
    GLL16(_s, _dp); GLL16(_s + 128 * KD, _dp + 8192); }

#define BSTAGE(bufx, kh, kt) {                                                 \
    const unsigned short* _s = bG + (size_t)(kt) * 64 + (kh) * 32;             \
    char* _dp = smem + 65536 + (bufx) * 32768 + (kh) * 16384 + w * 1024;       \
    GLL16(_s, _dp); GLL16(_s + 128 * KD, _dp + 8192); }

#define LOADB(bufx, ks) {                                                      \
    const char* _bb = smem + 65536 + (bufx) * 32768 + (ks) * 16384 + bR0;      \
    bk[ks][0] = *(const bf16x8*)(_bb);                                         \
    bk[ks][1] = *(const bf16x8*)(_bb + 1024);                                  \
    bk[ks][2] = *(const bf16x8*)(_bb + 2048);                                  \
    bk[ks][3] = *(const bf16x8*)(_bb + 3072); }

#define VMC2 asm volatile("s_waitcnt vmcnt(2)" ::: "memory")
#define VMC0 asm volatile("s_waitcnt vmcnt(0)" ::: "memory")

#define PHASE(bufx, mh, ks, LOADB_STMT, STAGE_STMT, VM_STMT) {                 \
    bf16x8 af[4];                                                              \
    const char* _ab = smem + (bufx) * 32768 + (ks) * 16384 + aR0 + (mh) * 4096;\
    af[0] = *(const bf16x8*)(_ab);                                             \
    af[1] = *(const bf16x8*)(_ab + 1024);                                      \
    af[2] = *(const bf16x8*)(_ab + 2048);                                      \
    af[3] = *(const bf16x8*)(_ab + 3072);                                      \
    LOADB_STMT;                                                                \
    STAGE_STMT;                                                                \
    VM_STMT;                                                                   \
    __builtin_amdgcn_s_barrier();                                              \
    asm volatile("s_waitcnt lgkmcnt(0)" ::: "memory");                         \
    __builtin_amdgcn_s_setprio(1);                                             \
    _Pragma("unroll") for (int _i = 0; _i < 4; ++_i)                           \
      _Pragma("unroll") for (int _n = 0; _n < 4; ++_n)                         \
        acc[(mh)*4+_i][_n] = __builtin_amdgcn_mfma_f32_16x16x32_bf16(          \
            af[_i], bk[ks][_n], acc[(mh)*4+_i][_n], 0, 0, 0);                  \
    __builtin_amdgcn_s_setprio(0);                                             \
    __builtin_amdgcn_s_barrier(); }

__global__ __launch_bounds__(512, 2) void gemm256_kernel(
    const unsigned short* __restrict__ A,   // [32768][1024] bf16
    const unsigned short* __restrict__ B,   // [1024][1024] bf16 (W row-major = B^T layout)
    float* __restrict__ C)                  // [32768][1024] f32
{
    __shared__ char smem[131072];

    const int t = threadIdx.x;
    const int w = t >> 6, l = t & 63;
    const int wm = w >> 2, wn = w & 3;

    // XCD-aware swizzle (nwg = 512, divisible by 8)
    const int bid = blockIdx.x;
    const int swz = (bid & 7) * 64 + (bid >> 3);
    const int tile_m = swz >> 2, tile_n = swz & 3;

    // staging source (per-lane, pre-swizzled granule)
    const int r0 = w * 16 + (l >> 2);              // row 0..127 within a 128-row group
    const int gsrc = (l & 3) ^ ((l >> 3) & 3);     // swizzled 16B k-granule
    const unsigned short* aG = A + (size_t)(tile_m * 256 + r0) * KD + gsrc * 8;
    const unsigned short* bG = B + (size_t)(tile_n * 256 + r0) * KD + gsrc * 8;

    // reader bases (byte offsets into smem)
    const int gq = (l >> 4) ^ ((l >> 1) & 3);      // swizzled granule for frag reads
    const int aR0 = (wm * 128 + (l & 15)) * 64 + gq * 16;
    const int bR0 = (wn * 64 + (l & 15)) * 64 + gq * 16;

    f32x4 acc[8][4] = {};
    bf16x8 bk[2][4];

    // prologue: tile0 all 4 halves + Ak0(tile1); then counted wait + barrier
    ASTAGE(0, 0, 0); ASTAGE(0, 1, 0); BSTAGE(0, 0, 0); BSTAGE(0, 1, 0);
    ASTAGE(1, 0, 1);
    VMC2;
    __builtin_amdgcn_s_barrier();

    for (int tt = 0; tt < 14; ++tt) {
        const int bc = tt & 1, bn = bc ^ 1;
        PHASE(bc, 0, 0, LOADB(bc, 0), ASTAGE(bn, 1, tt + 1), );
        PHASE(bc, 0, 1, LOADB(bc, 1), BSTAGE(bn, 0, tt + 1), );
        PHASE(bc, 1, 0,             , BSTAGE(bn, 1, tt + 1), );
        PHASE(bc, 1, 1,             , ASTAGE(bc, 0, tt + 2), VMC2);
    }
    // tt = 14 (stages tile 15 only; drain at q3)
    PHASE(0, 0, 0, LOADB(0, 0), ASTAGE(1, 1, 15), );
    PHASE(0, 0, 1, LOADB(0, 1), BSTAGE(1, 0, 15), );
    PHASE(0, 1, 0,            , BSTAGE(1, 1, 15), );
    PHASE(0, 1, 1,            ,                 , VMC0);
    // tt = 15 (no stages)
    PHASE(1, 0, 0, LOADB(1, 0), , );
    PHASE(1, 0, 1, LOADB(1, 1), , );
    PHASE(1, 1, 0,            , , );
    PHASE(1, 1, 1,            , , );

    // epilogue: C/D layout col=lane&15, row=(lane>>4)*4+reg
    float* Cp = C + (size_t)(tile_m * 256 + wm * 128 + ((l >> 4) * 4)) * ND
                  + tile_n * 256 + wn * 64 + (l & 15);
    #pragma unroll
    for (int m = 0; m < 8; ++m)
        #pragma unroll
        for (int n = 0; n < 4; ++n)
            #pragma unroll
            for (int j = 0; j < 4; ++j)
                Cp[(size_t)(m * 16 + j) * ND + n * 16] = acc[m][n][j];
}

extern "C" void kernel_launch(void* const* d_in, const int* in_sizes, int n_in,
                              void* d_out, int out_size, void* d_ws, size_t ws_size,
                              hipStream_t stream) {
    const float* x  = (const float*)d_in[0];   // [4,8192,1024] fp32
    const float* wt = (const float*)d_in[1];   // [1024,1024] fp32
    float* out = (float*)d_out;                // [4,8192,1024] fp32

    unsigned short* Abf = (unsigned short*)d_ws;                    // 64 MiB
    unsigned short* Wbf = Abf + (size_t)32768 * 1024;               // +2 MiB

    prune_scale_kernel<<<32768, 256, 0, stream>>>(x, Abf);
    wconv_kernel<<<1024, 256, 0, stream>>>(wt, Wbf);
    gemm256_kernel<<<512, 512, 0, stream>>>(Abf, Wbf, out);
}